// Round 3
// baseline (859.134 us; speedup 1.0000x reference)
//
#include <hip/hip_runtime.h>
#include <stdint.h>

#define COLS 16384
#define TPB  512
#define EPT  32            // elements per thread
#define NF4  8             // float4 loads per thread
#define CAP  2048          // candidate buffer (overflow prob ~e^-33 per row)
#define K    32

// Order-preserving float->uint key: larger float => larger key.
__device__ __forceinline__ uint32_t f2key(float f) {
    uint32_t u = __float_as_uint(f);
    return u ^ (uint32_t)(((int32_t)u >> 31) | 0x80000000u);
}

__global__ void __launch_bounds__(TPB, 6)
topk_relu_kernel(const float* __restrict__ x, float* __restrict__ out) {
    __shared__ uint32_t gmax[TPB / 16];      // 32 group maxes
    __shared__ uint32_t cand_key[CAP];
    __shared__ uint32_t cand_idx[CAP];
    __shared__ uint32_t bitmap[COLS / 32];   // 512 words: keep-flags per column
    __shared__ uint32_t cnt;
    __shared__ uint32_t sbcast;

    const int row = blockIdx.x;
    const int tid = threadIdx.x;
    const float4* xin  = (const float4*)(x   + (size_t)row * COLS);
    float4*       xout = (float4*)      (out + (size_t)row * COLS);

    // zero bitmap + counter (TPB == COLS/32 exactly: one word per thread)
    bitmap[tid] = 0;
    if (tid == 0) cnt = 0;

    // ---- load row -> sortable keys in registers; fold thread-local max ----
    uint32_t keys[EPT];
    uint32_t tmax = 0;
    #pragma unroll
    for (int j = 0; j < NF4; ++j) {
        float4 v = xin[j * TPB + tid];
        uint32_t k0 = f2key(v.x), k1 = f2key(v.y);
        uint32_t k2 = f2key(v.z), k3 = f2key(v.w);
        keys[4*j+0] = k0; keys[4*j+1] = k1;
        keys[4*j+2] = k2; keys[4*j+3] = k3;
        uint32_t m01 = k0 > k1 ? k0 : k1;
        uint32_t m23 = k2 > k3 ? k2 : k3;
        uint32_t m   = m01 > m23 ? m01 : m23;
        tmax = m > tmax ? m : tmax;
    }

    // ---- group max over 16 consecutive lanes (xor masks < 16 stay in-group)
    #pragma unroll
    for (int m = 1; m < 16; m <<= 1) {
        uint32_t o = (uint32_t)__shfl_xor((int)tmax, m);
        tmax = o > tmax ? o : tmax;
    }
    if ((tid & 15) == 0) gmax[tid >> 4] = tmax;
    __syncthreads();

    // ---- S = min of 32 group maxes (provably <= row's 32nd-largest) ----
    if (tid < 32) {
        uint32_t v = gmax[tid];
        #pragma unroll
        for (int m = 1; m < 32; m <<= 1) {
            uint32_t o = (uint32_t)__shfl_xor((int)v, m);
            v = o < v ? o : v;
        }
        if (tid == 0) sbcast = v;
    }
    __syncthreads();
    const uint32_t S = sbcast;

    // ---- gather candidates (key >= S); ~100-200 expected ----
    #pragma unroll
    for (int e = 0; e < EPT; ++e) {
        if (keys[e] >= S) {
            uint32_t p = atomicAdd(&cnt, 1u);
            if (p < CAP) {
                cand_key[p] = keys[e];
                cand_idx[p] = (uint32_t)((((e >> 2) * TPB + tid) << 2) + (e & 3));
            }
        }
    }
    __syncthreads();

    // ---- exact resolve: rank by (key desc, idx asc); rank < K -> keep ----
    uint32_t n = cnt; if (n > CAP) n = CAP;
    for (uint32_t t = tid; t < n; t += TPB) {
        uint32_t myk = cand_key[t], myi = cand_idx[t];
        uint32_t rank = 0;
        for (uint32_t j = 0; j < n; ++j) {        // LDS broadcast reads
            uint32_t kj = cand_key[j];
            rank += (kj > myk) || (kj == myk && cand_idx[j] < myi);
        }
        if (rank < K) atomicOr(&bitmap[myi >> 5], 1u << (myi & 31));
    }
    __syncthreads();

    // ---- output: relu(value) at kept positions, 0 elsewhere ----
    #pragma unroll
    for (int j = 0; j < NF4; ++j) {
        uint32_t base = (uint32_t)((j * TPB + tid) << 2);   // column of .x
        uint32_t w = bitmap[base >> 5];
        float4 o;
        float* op = (float*)&o;
        #pragma unroll
        for (int c = 0; c < 4; ++c) {
            uint32_t kk = keys[4*j + c];
            bool keep = (w >> ((base & 31) + c)) & 1u;
            op[c] = (keep && kk > 0x80000000u)
                        ? __uint_as_float(kk ^ 0x80000000u) : 0.0f;
        }
        xout[j * TPB + tid] = o;
    }
}

extern "C" void kernel_launch(void* const* d_in, const int* in_sizes, int n_in,
                              void* d_out, int out_size, void* d_ws, size_t ws_size,
                              hipStream_t stream) {
    const float* x = (const float*)d_in[0];
    float* out = (float*)d_out;
    const int rows = in_sizes[0] / COLS;
    topk_relu_kernel<<<rows, TPB, 0, stream>>>(x, out);
}